// Round 1
// baseline (2735.879 us; speedup 1.0000x reference)
//
#include <hip/hip_runtime.h>

typedef _Float16 f16;
typedef _Float16 half8 __attribute__((ext_vector_type(8)));
typedef float f32x4 __attribute__((ext_vector_type(4)));
typedef unsigned int u32;

#define B_    16384
#define E_    6
#define ASTR  1088     // row stride of activation buffers (f16 elements)
#define AOUT  512

// XOR swizzle: tile rows are 64 f16 = 128B = 8 chunks of 16B.
// Physical chunk = logical chunk ^ (row & 7). Used for BOTH ds_write and ds_read.
__device__ __forceinline__ u32 swz(u32 row, u32 ch) {
  return row * 128u + ((ch ^ (row & 7u)) * 16u);
}

__device__ __forceinline__ float elu_f(float x) {
  return x > 0.f ? x : (__expf(x) - 1.f);
}

// Reproduce jax.random.normal(jax.random.key(42), (B,512), f32)[idx]
// threefry2x32, partitionable mode: bits[idx] = x0^x1 of block (hi=0, lo=idx), key=(0,42)
// then uniform(nextafter(-1,0), 1) -> sqrt(2)*erfinv (XLA/Giles f32 polynomial)
__device__ __forceinline__ float jax_eps(u32 idx) {
  const u32 k0 = 0u, k1 = 42u;
  const u32 k2 = k0 ^ k1 ^ 0x1BD11BDAu;
  u32 x0 = 0u + k0, x1 = idx + k1;
#define TFR(r) { x0 += x1; x1 = (x1 << (r)) | (x1 >> (32 - (r))); x1 ^= x0; }
  TFR(13) TFR(15) TFR(26) TFR(6)   x0 += k1; x1 += k2 + 1u;
  TFR(17) TFR(29) TFR(16) TFR(24)  x0 += k2; x1 += k0 + 2u;
  TFR(13) TFR(15) TFR(26) TFR(6)   x0 += k0; x1 += k1 + 3u;
  TFR(17) TFR(29) TFR(16) TFR(24)  x0 += k1; x1 += k2 + 4u;
  TFR(13) TFR(15) TFR(26) TFR(6)   x0 += k2; x1 += k0 + 5u;
#undef TFR
  u32 bits = x0 ^ x1;
  float f = __uint_as_float(0x3f800000u | (bits >> 9)) - 1.0f;  // [0,1)
  const float lo = -0.99999994f;                                 // nextafter(-1,0)
  float u = fmaxf(lo, fmaf(f, 2.0f, lo));                        // (maxval-minval) rounds to 2.0f
  float w = -__logf(fmaf(-u, u, 1.0f));
  float p;
  if (w < 5.0f) {
    w -= 2.5f;
    p = 2.81022636e-08f;
    p = fmaf(p, w, 3.43273939e-07f);
    p = fmaf(p, w, -3.5233877e-06f);
    p = fmaf(p, w, -4.39150654e-06f);
    p = fmaf(p, w, 0.00021858087f);
    p = fmaf(p, w, -0.00125372503f);
    p = fmaf(p, w, -0.00417768164f);
    p = fmaf(p, w, 0.246640727f);
    p = fmaf(p, w, 1.50140941f);
  } else {
    w = __fsqrt_rn(w) - 3.0f;
    p = -0.000200214257f;
    p = fmaf(p, w, 0.000100950558f);
    p = fmaf(p, w, 0.00134934322f);
    p = fmaf(p, w, -0.00367342844f);
    p = fmaf(p, w, 0.00573950773f);
    p = fmaf(p, w, -0.0076224613f);
    p = fmaf(p, w, 0.00943887047f);
    p = fmaf(p, w, 1.00167406f);
    p = fmaf(p, w, 2.83297682f);
  }
  return 1.41421356f * p * u;
}

// ---------------- prep: activations (state+latent -> f16 buffers) ----------------
__global__ void prep_act(const float* __restrict__ state, const float* __restrict__ latent,
                         f16* __restrict__ actA, f16* __restrict__ actB) {
  const u32 NS = (B_ * 512u) / 8u;   // 1048576
  const u32 NL = (B_ * 64u) / 8u;    // 131072
  u32 i = blockIdx.x * 256u + threadIdx.x;
  if (i < NS) {
    u32 e = i * 8u;
    u32 b = e >> 9, c = e & 511u;
    float4 v0 = *(const float4*)(state + e);
    float4 v1 = *(const float4*)(state + e + 4);
    half8 h;
    h[0]=(f16)v0.x; h[1]=(f16)v0.y; h[2]=(f16)v0.z; h[3]=(f16)v0.w;
    h[4]=(f16)v1.x; h[5]=(f16)v1.y; h[6]=(f16)v1.z; h[7]=(f16)v1.w;
    *(half8*)(actA + (size_t)b * ASTR + c) = h;
  } else if (i < NS + NL) {
    u32 e = (i - NS) * 8u;
    u32 b = e >> 6, c = e & 63u;
    float4 v0 = *(const float4*)(latent + e);
    float4 v1 = *(const float4*)(latent + e + 4);
    half8 h;
    h[0]=(f16)v0.x; h[1]=(f16)v0.y; h[2]=(f16)v0.z; h[3]=(f16)v0.w;
    h[4]=(f16)v1.x; h[5]=(f16)v1.y; h[6]=(f16)v1.z; h[7]=(f16)v1.w;
    *(half8*)(actA + (size_t)b * ASTR + 512 + c) = h;   // layer0 input cols 512..575
    *(half8*)(actA + (size_t)b * ASTR + 1024 + c) = h;  // layer2 input cols 1024..1087
    *(half8*)(actB + (size_t)b * ASTR + 1024 + c) = h;  // layer1/3 input cols 1024..1087
  }
}

// ---------------- prep: gating W0 transpose + hi/lo split ----------------
__global__ void prep_gw0(const float* __restrict__ gw0, f16* __restrict__ g0hi,
                         f16* __restrict__ g0lo) {
  int i = blockIdx.x * 256 + threadIdx.x;  // over 32*576
  if (i < 32 * 576) {
    int n = i / 576, j = i % 576;
    float v = gw0[j * 32 + n];
    f16 h = (f16)v;
    g0hi[i] = h;
    g0lo[i] = (f16)(v - (float)h);
  }
}

// ---------------- prep: expert-weight transpose+convert w[e][j][k] -> wt[e][k][j] f16 ---
__global__ void transpose_w(const float* __restrict__ w, f16* __restrict__ wt,
                            int J, int K) {
  __shared__ float t[64][65];
  int tiles_j = J >> 6, tiles_k = K >> 6;
  int per_e = tiles_j * tiles_k;
  int bid = blockIdx.x;
  int e = bid / per_e, rem = bid % per_e;
  int jt = rem / tiles_k, kt = rem % tiles_k;
  int tid = threadIdx.x;
  int r = tid >> 2, c0 = (tid & 3) << 4;
  const float* src = w + ((size_t)e * J + (size_t)jt * 64 + r) * K + (size_t)kt * 64 + c0;
  float4 v0 = *(const float4*)(src);
  float4 v1 = *(const float4*)(src + 4);
  float4 v2 = *(const float4*)(src + 8);
  float4 v3 = *(const float4*)(src + 12);
  t[r][c0+0]=v0.x;  t[r][c0+1]=v0.y;  t[r][c0+2]=v0.z;  t[r][c0+3]=v0.w;
  t[r][c0+4]=v1.x;  t[r][c0+5]=v1.y;  t[r][c0+6]=v1.z;  t[r][c0+7]=v1.w;
  t[r][c0+8]=v2.x;  t[r][c0+9]=v2.y;  t[r][c0+10]=v2.z; t[r][c0+11]=v2.w;
  t[r][c0+12]=v3.x; t[r][c0+13]=v3.y; t[r][c0+14]=v3.z; t[r][c0+15]=v3.w;
  __syncthreads();
  int kr = tid >> 2, jq = (tid & 3) << 4;
  half8 p0, p1;
#pragma unroll
  for (int m = 0; m < 8; m++) {
    p0[m] = (f16)t[jq + m][kr];
    p1[m] = (f16)t[jq + 8 + m][kr];
  }
  f16* dst = wt + ((size_t)e * K + (size_t)kt * 64 + kr) * J + (size_t)jt * 64 + jq;
  *(half8*)(dst) = p0;
  *(half8*)(dst + 8) = p1;
}

// ---------------- gating MLP: coefT[e][b] = softmax over experts -----------------
// layer0 via split-f16 MFMA (f32-accurate), layers 1-2 tiny f32 VALU
__global__ __launch_bounds__(256) void gating_kernel(
    const float* __restrict__ state, const float* __restrict__ latent,
    const f16* __restrict__ g0hi, const f16* __restrict__ g0lo,
    const float* __restrict__ gb0, const float* __restrict__ gw1,
    const float* __restrict__ gb1, const float* __restrict__ gw2,
    const float* __restrict__ gb2, float* __restrict__ coefT) {
  __shared__ __align__(16) char sm[24576];  // Ahi 8K | Alo 8K | Bhi 4K | Blo 4K
  __shared__ float h_lds[64][33];
  char* Ahi = sm;
  char* Alo = sm + 8192;
  char* Bhi = sm + 16384;
  char* Blo = sm + 20480;
  const int tid = threadIdx.x, lane = tid & 63, wave = tid >> 6;
  const int b0 = blockIdx.x * 64;

  f32x4 acc[2];
#pragma unroll
  for (int n = 0; n < 2; n++) {
    float v = gb0[n * 16 + (lane & 15)];
    f32x4 t = {v, v, v, v};
    acc[n] = t;
  }

  for (int kt = 0; kt < 9; ++kt) {
    __syncthreads();
    // stage Xc tile [64][64]: hi/lo split
    int r = tid >> 2, cq = (tid & 3) << 4;
    float xv[16];
    if (kt < 8) {
      const float* s = state + (size_t)(b0 + r) * 512 + kt * 64 + cq;
      *(float4*)(xv)      = *(const float4*)(s);
      *(float4*)(xv + 4)  = *(const float4*)(s + 4);
      *(float4*)(xv + 8)  = *(const float4*)(s + 8);
      *(float4*)(xv + 12) = *(const float4*)(s + 12);
    } else {
      const float* s = latent + (size_t)(b0 + r) * 64 + cq;
      *(float4*)(xv)      = *(const float4*)(s);
      *(float4*)(xv + 4)  = *(const float4*)(s + 4);
      *(float4*)(xv + 8)  = *(const float4*)(s + 8);
      *(float4*)(xv + 12) = *(const float4*)(s + 12);
    }
    half8 hh[2], hl[2];
#pragma unroll
    for (int q = 0; q < 2; q++)
#pragma unroll
      for (int i = 0; i < 8; i++) {
        float x = xv[q * 8 + i];
        f16 h = (f16)x;
        hh[q][i] = h;
        hl[q][i] = (f16)(x - (float)h);
      }
    *(half8*)(Ahi + swz(r, (tid & 3) * 2 + 0)) = hh[0];
    *(half8*)(Ahi + swz(r, (tid & 3) * 2 + 1)) = hh[1];
    *(half8*)(Alo + swz(r, (tid & 3) * 2 + 0)) = hl[0];
    *(half8*)(Alo + swz(r, (tid & 3) * 2 + 1)) = hl[1];
    // stage gw0T tile [32][64]
    int nb = tid >> 3, chb = tid & 7;
    half8 bh = *(const half8*)(g0hi + (size_t)nb * 576 + kt * 64 + chb * 8);
    half8 bl = *(const half8*)(g0lo + (size_t)nb * 576 + kt * 64 + chb * 8);
    *(half8*)(Bhi + swz(nb, chb)) = bh;
    *(half8*)(Blo + swz(nb, chb)) = bl;
    __syncthreads();
    // compute: wave handles rows wave*16..+16
#pragma unroll
    for (int ks = 0; ks < 2; ks++) {
      int arow = wave * 16 + (lane & 15);
      int ch = ks * 4 + (lane >> 4);
      half8 ah = *(const half8*)(Ahi + swz(arow, ch));
      half8 al = *(const half8*)(Alo + swz(arow, ch));
#pragma unroll
      for (int n = 0; n < 2; n++) {
        int brow = n * 16 + (lane & 15);
        half8 wh = *(const half8*)(Bhi + swz(brow, ch));
        half8 wl = *(const half8*)(Blo + swz(brow, ch));
        acc[n] = __builtin_amdgcn_mfma_f32_16x16x32_f16(ah, wh, acc[n], 0, 0, 0);
        acc[n] = __builtin_amdgcn_mfma_f32_16x16x32_f16(al, wh, acc[n], 0, 0, 0);
        acc[n] = __builtin_amdgcn_mfma_f32_16x16x32_f16(ah, wl, acc[n], 0, 0, 0);
      }
    }
  }
  // h1 = elu(.) -> LDS
#pragma unroll
  for (int n = 0; n < 2; n++)
#pragma unroll
    for (int i = 0; i < 4; i++) {
      int row = wave * 16 + (lane >> 4) * 4 + i;
      int col = n * 16 + (lane & 15);
      h_lds[row][col] = elu_f(acc[n][i]);
    }
  __syncthreads();
  // layer 1: h2 = elu(h1 @ gw1 + gb1)
  {
    int row = tid & 63, q = tid >> 6;
    float a2[8];
#pragma unroll
    for (int o = 0; o < 8; o++) a2[o] = gb1[q * 8 + o];
    for (int j = 0; j < 32; j++) {
      float v = h_lds[row][j];
#pragma unroll
      for (int o = 0; o < 8; o++) a2[o] = fmaf(v, gw1[j * 32 + q * 8 + o], a2[o]);
    }
    __syncthreads();
#pragma unroll
    for (int o = 0; o < 8; o++) h_lds[row][q * 8 + o] = elu_f(a2[o]);
  }
  __syncthreads();
  // layer 2 + softmax (wave 0 only; 64 rows)
  if (wave == 0) {
    float lg[6];
#pragma unroll
    for (int e = 0; e < 6; e++) lg[e] = gb2[e];
    for (int j = 0; j < 32; j++) {
      float v = h_lds[lane][j];
#pragma unroll
      for (int e = 0; e < 6; e++) lg[e] = fmaf(v, gw2[j * 6 + e], lg[e]);
    }
    float mx = lg[0];
#pragma unroll
    for (int e = 1; e < 6; e++) mx = fmaxf(mx, lg[e]);
    float s = 0.f, pc[6];
#pragma unroll
    for (int e = 0; e < 6; e++) { pc[e] = __expf(lg[e] - mx); s += pc[e]; }
    float inv = 1.0f / s;
#pragma unroll
    for (int e = 0; e < 6; e++) coefT[e * B_ + b0 + lane] = pc[e] * inv;
  }
}

// ---------------- main mixed-expert GEMM -----------------------------------------
// C[b, k] = sum_e coefT[e][b] * ( X[b,:J] @ Wt[e][k][:J]^T + bias[e][k] )
// MODE 0: out_act[b*ASTR + k] = f16(elu(C));  MODE 1: out_f32[b*512+k] = C + 0.05*eps
template <int J, int KOUT, int MODE>
__global__ __launch_bounds__(256, 2) void moe_gemm(
    const f16* __restrict__ act, const f16* __restrict__ wt,
    const float* __restrict__ coefT, const float* __restrict__ bias,
    f16* __restrict__ out_act, float* __restrict__ out_f32) {
  constexpr int NSUB = J / 64;
  constexpr int NT = E_ * NSUB;
  constexpr int NTILE = KOUT / 128;
  __shared__ __align__(16) char sm[32768];
  char* As = sm;
  char* Bs = sm + 16384;

  const int tid = threadIdx.x;
  const int lane = tid & 63;
  const int wave = tid >> 6;
  const int wr = wave >> 1, wc = wave & 1;
  // XCD-bijective block swizzle (grid % 8 == 0)
  const int nwg = gridDim.x;
  const int cpx = nwg >> 3;
  const int bid = (blockIdx.x & 7) * cpx + (blockIdx.x >> 3);
  const int b0 = (bid / NTILE) * 128;
  const int n0 = (bid % NTILE) * 128;

  f32x4 accM[4][4];
  f32x4 accE[4][4];
  const f32x4 zero4 = {0.f, 0.f, 0.f, 0.f};
#pragma unroll
  for (int m = 0; m < 4; m++)
#pragma unroll
    for (int n = 0; n < 4; n++) accM[m][n] = zero4;

  auto initE = [&](int e) {
#pragma unroll
    for (int n = 0; n < 4; n++) {
      float v = bias[e * KOUT + n0 + wc * 64 + n * 16 + (lane & 15)];
      f32x4 t = {v, v, v, v};
#pragma unroll
      for (int m = 0; m < 4; m++) accE[m][n] = t;
    }
  };
  initE(0);

  uint4 aReg[4], bReg[4];
  auto loadTile = [&](int kt) {
    int e = kt / NSUB, ks = kt % NSUB;
    const f16* aSrc = act + (size_t)b0 * ASTR + ks * 64;
    const f16* bSrc = wt + ((size_t)e * KOUT + n0) * J + ks * 64;
#pragma unroll
    for (int i = 0; i < 4; i++) {
      int c = tid + i * 256;
      int row = c >> 3, ch = c & 7;
      aReg[i] = *(const uint4*)(aSrc + (size_t)row * ASTR + ch * 8);
      bReg[i] = *(const uint4*)(bSrc + (size_t)row * J + ch * 8);
    }
  };
  loadTile(0);

  for (int kt = 0; kt < NT; ++kt) {
    __syncthreads();
#pragma unroll
    for (int i = 0; i < 4; i++) {
      int c = tid + i * 256;
      int row = c >> 3, ch = c & 7;
      *(uint4*)(As + swz(row, ch)) = aReg[i];
      *(uint4*)(Bs + swz(row, ch)) = bReg[i];
    }
    __syncthreads();
    if (kt + 1 < NT) loadTile(kt + 1);  // prefetch next tile into regs (overlaps MFMA)
#pragma unroll
    for (int ks2 = 0; ks2 < 2; ++ks2) {
      half8 af[4], bf[4];
#pragma unroll
      for (int m = 0; m < 4; m++) {
        int row = wr * 64 + m * 16 + (lane & 15);
        af[m] = *(const half8*)(As + swz(row, ks2 * 4 + (lane >> 4)));
      }
#pragma unroll
      for (int n = 0; n < 4; n++) {
        int rn = wc * 64 + n * 16 + (lane & 15);
        bf[n] = *(const half8*)(Bs + swz(rn, ks2 * 4 + (lane >> 4)));
      }
#pragma unroll
      for (int m = 0; m < 4; m++)
#pragma unroll
        for (int n = 0; n < 4; n++)
          accE[m][n] = __builtin_amdgcn_mfma_f32_16x16x32_f16(af[m], bf[n], accE[m][n], 0, 0, 0);
    }
    int e = kt / NSUB, ks = kt % NSUB;
    if (ks == NSUB - 1) {
      // expert boundary: accM += coef[row,e] * (X@We + be)
#pragma unroll
      for (int m = 0; m < 4; m++)
#pragma unroll
        for (int i = 0; i < 4; i++) {
          int row = b0 + wr * 64 + m * 16 + (lane >> 4) * 4 + i;
          float cf = coefT[e * B_ + row];
#pragma unroll
          for (int n = 0; n < 4; n++) accM[m][n][i] = fmaf(cf, accE[m][n][i], accM[m][n][i]);
        }
      if (e + 1 < E_) initE(e + 1);
    }
  }
  // epilogue
#pragma unroll
  for (int m = 0; m < 4; m++)
#pragma unroll
    for (int n = 0; n < 4; n++)
#pragma unroll
      for (int i = 0; i < 4; i++) {
        int row = b0 + wr * 64 + m * 16 + (lane >> 4) * 4 + i;
        int col = n0 + wc * 64 + n * 16 + (lane & 15);
        float x = accM[m][n][i];
        if (MODE == 0) {
          out_act[(size_t)row * ASTR + col] = (f16)elu_f(x);
        } else {
          u32 idx = (u32)row * AOUT + col;
          out_f32[idx] = fmaf(0.05f, jax_eps(idx), x);
        }
      }
}

// ---------------- launch ----------------------------------------------------------
extern "C" void kernel_launch(void* const* d_in, const int* in_sizes, int n_in,
                              void* d_out, int out_size, void* d_ws, size_t ws_size,
                              hipStream_t stream) {
  (void)in_sizes; (void)n_in; (void)out_size; (void)ws_size;
  const float* state  = (const float*)d_in[0];
  const float* latent = (const float*)d_in[1];
  const float* w0 = (const float*)d_in[2];
  const float* b0 = (const float*)d_in[3];
  const float* w1 = (const float*)d_in[4];
  const float* b1 = (const float*)d_in[5];
  const float* w2 = (const float*)d_in[6];
  const float* b2 = (const float*)d_in[7];
  const float* w3 = (const float*)d_in[8];
  const float* b3 = (const float*)d_in[9];
  const float* gw0 = (const float*)d_in[10];
  const float* gb0 = (const float*)d_in[11];
  const float* gw1 = (const float*)d_in[12];
  const float* gb1 = (const float*)d_in[13];
  const float* gw2 = (const float*)d_in[14];
  const float* gb2 = (const float*)d_in[15];

  char* ws = (char*)d_ws;
  size_t off = 0;
  float* coefT = (float*)(ws + off); off += (size_t)E_ * B_ * 4;
  f16* actA = (f16*)(ws + off); off += (size_t)B_ * ASTR * 2;
  f16* actB = (f16*)(ws + off); off += (size_t)B_ * ASTR * 2;
  f16* wt0 = (f16*)(ws + off); off += (size_t)E_ * 1024 * 576 * 2;
  f16* wt1 = (f16*)(ws + off); off += (size_t)E_ * 1024 * 1088 * 2;
  f16* wt2 = (f16*)(ws + off); off += (size_t)E_ * 1024 * 1088 * 2;
  f16* wt3 = (f16*)(ws + off); off += (size_t)E_ * 512 * 1088 * 2;
  f16* g0hi = (f16*)(ws + off); off += 32 * 576 * 2;
  f16* g0lo = (f16*)(ws + off); off += 32 * 576 * 2;

  prep_act<<<4608, 256, 0, stream>>>(state, latent, actA, actB);
  prep_gw0<<<72, 256, 0, stream>>>(gw0, g0hi, g0lo);
  transpose_w<<<6 * 9 * 16, 256, 0, stream>>>(w0, wt0, 576, 1024);
  transpose_w<<<6 * 17 * 16, 256, 0, stream>>>(w1, wt1, 1088, 1024);
  transpose_w<<<6 * 17 * 16, 256, 0, stream>>>(w2, wt2, 1088, 1024);
  transpose_w<<<6 * 17 * 8, 256, 0, stream>>>(w3, wt3, 1088, 512);
  gating_kernel<<<256, 256, 0, stream>>>(state, latent, g0hi, g0lo, gb0, gw1, gb1,
                                         gw2, gb2, coefT);
  moe_gemm<576, 1024, 0><<<1024, 256, 0, stream>>>(actA, wt0, coefT, b0, actB, nullptr);
  moe_gemm<1088, 1024, 0><<<1024, 256, 0, stream>>>(actB, wt1, coefT, b1, actA, nullptr);
  moe_gemm<1088, 1024, 0><<<1024, 256, 0, stream>>>(actA, wt2, coefT, b2, actB, nullptr);
  moe_gemm<1088, 512, 1><<<512, 256, 0, stream>>>(actB, wt3, coefT, b3, nullptr, (float*)d_out);
}

// Round 2
// 1597.456 us; speedup vs baseline: 1.7126x; 1.7126x over previous
//
#include <hip/hip_runtime.h>

typedef _Float16 f16;
typedef _Float16 half8 __attribute__((ext_vector_type(8)));
typedef float f32x4 __attribute__((ext_vector_type(4)));
typedef unsigned int u32;

#define B_    16384
#define E_    6
#define ASTR  1088     // row stride of activation buffers (f16 elements)
#define AOUT  512

// XOR swizzle: tile rows are 64 f16 = 128B = 8 chunks of 16B.
// Physical chunk = logical chunk ^ (row & 7). Used for BOTH ds_write and ds_read.
__device__ __forceinline__ u32 swz(u32 row, u32 ch) {
  return row * 128u + ((ch ^ (row & 7u)) * 16u);
}

__device__ __forceinline__ float elu_f(float x) {
  return x > 0.f ? x : (__expf(x) - 1.f);
}

__device__ __forceinline__ half8 splat8(f16 s) {
  half8 v = {s, s, s, s, s, s, s, s};
  return v;
}

// Reproduce jax.random.normal(jax.random.key(42), (B,512), f32)[idx]
// threefry2x32, partitionable mode: bits[idx] = x0^x1 of block (hi=0, lo=idx), key=(0,42)
// then uniform(nextafter(-1,0), 1) -> sqrt(2)*erfinv (XLA/Giles f32 polynomial)
__device__ __forceinline__ float jax_eps(u32 idx) {
  const u32 k0 = 0u, k1 = 42u;
  const u32 k2 = k0 ^ k1 ^ 0x1BD11BDAu;
  u32 x0 = 0u + k0, x1 = idx + k1;
#define TFR(r) { x0 += x1; x1 = (x1 << (r)) | (x1 >> (32 - (r))); x1 ^= x0; }
  TFR(13) TFR(15) TFR(26) TFR(6)   x0 += k1; x1 += k2 + 1u;
  TFR(17) TFR(29) TFR(16) TFR(24)  x0 += k2; x1 += k0 + 2u;
  TFR(13) TFR(15) TFR(26) TFR(6)   x0 += k0; x1 += k1 + 3u;
  TFR(17) TFR(29) TFR(16) TFR(24)  x0 += k1; x1 += k2 + 4u;
  TFR(13) TFR(15) TFR(26) TFR(6)   x0 += k2; x1 += k0 + 5u;
#undef TFR
  u32 bits = x0 ^ x1;
  float f = __uint_as_float(0x3f800000u | (bits >> 9)) - 1.0f;  // [0,1)
  const float lo = -0.99999994f;                                 // nextafter(-1,0)
  float u = fmaxf(lo, fmaf(f, 2.0f, lo));                        // (maxval-minval) rounds to 2.0f
  float w = -__logf(fmaf(-u, u, 1.0f));
  float p;
  if (w < 5.0f) {
    w -= 2.5f;
    p = 2.81022636e-08f;
    p = fmaf(p, w, 3.43273939e-07f);
    p = fmaf(p, w, -3.5233877e-06f);
    p = fmaf(p, w, -4.39150654e-06f);
    p = fmaf(p, w, 0.00021858087f);
    p = fmaf(p, w, -0.00125372503f);
    p = fmaf(p, w, -0.00417768164f);
    p = fmaf(p, w, 0.246640727f);
    p = fmaf(p, w, 1.50140941f);
  } else {
    w = __fsqrt_rn(w) - 3.0f;
    p = -0.000200214257f;
    p = fmaf(p, w, 0.000100950558f);
    p = fmaf(p, w, 0.00134934322f);
    p = fmaf(p, w, -0.00367342844f);
    p = fmaf(p, w, 0.00573950773f);
    p = fmaf(p, w, -0.0076224613f);
    p = fmaf(p, w, 0.00943887047f);
    p = fmaf(p, w, 1.00167406f);
    p = fmaf(p, w, 2.83297682f);
  }
  return 1.41421356f * p * u;
}

// ---------------- prep: activations (state+latent -> f16 buffers) ----------------
__global__ void prep_act(const float* __restrict__ state, const float* __restrict__ latent,
                         f16* __restrict__ actA, f16* __restrict__ actB) {
  const u32 NS = (B_ * 512u) / 8u;   // 1048576
  const u32 NL = (B_ * 64u) / 8u;    // 131072
  u32 i = blockIdx.x * 256u + threadIdx.x;
  if (i < NS) {
    u32 e = i * 8u;
    u32 b = e >> 9, c = e & 511u;
    float4 v0 = *(const float4*)(state + e);
    float4 v1 = *(const float4*)(state + e + 4);
    half8 h;
    h[0]=(f16)v0.x; h[1]=(f16)v0.y; h[2]=(f16)v0.z; h[3]=(f16)v0.w;
    h[4]=(f16)v1.x; h[5]=(f16)v1.y; h[6]=(f16)v1.z; h[7]=(f16)v1.w;
    *(half8*)(actA + (size_t)b * ASTR + c) = h;
  } else if (i < NS + NL) {
    u32 e = (i - NS) * 8u;
    u32 b = e >> 6, c = e & 63u;
    float4 v0 = *(const float4*)(latent + e);
    float4 v1 = *(const float4*)(latent + e + 4);
    half8 h;
    h[0]=(f16)v0.x; h[1]=(f16)v0.y; h[2]=(f16)v0.z; h[3]=(f16)v0.w;
    h[4]=(f16)v1.x; h[5]=(f16)v1.y; h[6]=(f16)v1.z; h[7]=(f16)v1.w;
    *(half8*)(actA + (size_t)b * ASTR + 512 + c) = h;   // layer0 input cols 512..575
    *(half8*)(actA + (size_t)b * ASTR + 1024 + c) = h;  // layer2 input cols 1024..1087
    *(half8*)(actB + (size_t)b * ASTR + 1024 + c) = h;  // layer1/3 input cols 1024..1087
  }
}

// ---------------- prep: gating W0 transpose + hi/lo split ----------------
__global__ void prep_gw0(const float* __restrict__ gw0, f16* __restrict__ g0hi,
                         f16* __restrict__ g0lo) {
  int i = blockIdx.x * 256 + threadIdx.x;  // over 32*576
  if (i < 32 * 576) {
    int n = i / 576, j = i % 576;
    float v = gw0[j * 32 + n];
    f16 h = (f16)v;
    g0hi[i] = h;
    g0lo[i] = (f16)(v - (float)h);
  }
}

// ---------------- prep: expert-weight transpose+convert w[e][j][k] -> wt[e][k][j] f16 ---
__global__ void transpose_w(const float* __restrict__ w, f16* __restrict__ wt,
                            int J, int K) {
  __shared__ float t[64][65];
  int tiles_j = J >> 6, tiles_k = K >> 6;
  int per_e = tiles_j * tiles_k;
  int bid = blockIdx.x;
  int e = bid / per_e, rem = bid % per_e;
  int jt = rem / tiles_k, kt = rem % tiles_k;
  int tid = threadIdx.x;
  int r = tid >> 2, c0 = (tid & 3) << 4;
  const float* src = w + ((size_t)e * J + (size_t)jt * 64 + r) * K + (size_t)kt * 64 + c0;
  float4 v0 = *(const float4*)(src);
  float4 v1 = *(const float4*)(src + 4);
  float4 v2 = *(const float4*)(src + 8);
  float4 v3 = *(const float4*)(src + 12);
  t[r][c0+0]=v0.x;  t[r][c0+1]=v0.y;  t[r][c0+2]=v0.z;  t[r][c0+3]=v0.w;
  t[r][c0+4]=v1.x;  t[r][c0+5]=v1.y;  t[r][c0+6]=v1.z;  t[r][c0+7]=v1.w;
  t[r][c0+8]=v2.x;  t[r][c0+9]=v2.y;  t[r][c0+10]=v2.z; t[r][c0+11]=v2.w;
  t[r][c0+12]=v3.x; t[r][c0+13]=v3.y; t[r][c0+14]=v3.z; t[r][c0+15]=v3.w;
  __syncthreads();
  int kr = tid >> 2, jq = (tid & 3) << 4;
  half8 p0, p1;
#pragma unroll
  for (int m = 0; m < 8; m++) {
    p0[m] = (f16)t[jq + m][kr];
    p1[m] = (f16)t[jq + 8 + m][kr];
  }
  f16* dst = wt + ((size_t)e * K + (size_t)kt * 64 + kr) * J + (size_t)jt * 64 + jq;
  *(half8*)(dst) = p0;
  *(half8*)(dst + 8) = p1;
}

// ---------------- gating MLP: coefT[e][b] = softmax over experts -----------------
// layer0 via split-f16 MFMA (f32-accurate), layers 1-2 tiny f32 VALU
__global__ __launch_bounds__(256) void gating_kernel(
    const float* __restrict__ state, const float* __restrict__ latent,
    const f16* __restrict__ g0hi, const f16* __restrict__ g0lo,
    const float* __restrict__ gb0, const float* __restrict__ gw1,
    const float* __restrict__ gb1, const float* __restrict__ gw2,
    const float* __restrict__ gb2, float* __restrict__ coefT) {
  __shared__ __align__(16) char sm[24576];  // Ahi 8K | Alo 8K | Bhi 4K | Blo 4K
  __shared__ float h_lds[64][33];
  char* Ahi = sm;
  char* Alo = sm + 8192;
  char* Bhi = sm + 16384;
  char* Blo = sm + 20480;
  const int tid = threadIdx.x, lane = tid & 63, wave = tid >> 6;
  const int b0 = blockIdx.x * 64;

  f32x4 acc[2];
#pragma unroll
  for (int n = 0; n < 2; n++) {
    float v = gb0[n * 16 + (lane & 15)];
    f32x4 t = {v, v, v, v};
    acc[n] = t;
  }

  for (int kt = 0; kt < 9; ++kt) {
    __syncthreads();
    // stage Xc tile [64][64]: hi/lo split
    int r = tid >> 2, cq = (tid & 3) << 4;
    float xv[16];
    if (kt < 8) {
      const float* s = state + (size_t)(b0 + r) * 512 + kt * 64 + cq;
      *(float4*)(xv)      = *(const float4*)(s);
      *(float4*)(xv + 4)  = *(const float4*)(s + 4);
      *(float4*)(xv + 8)  = *(const float4*)(s + 8);
      *(float4*)(xv + 12) = *(const float4*)(s + 12);
    } else {
      const float* s = latent + (size_t)(b0 + r) * 64 + cq;
      *(float4*)(xv)      = *(const float4*)(s);
      *(float4*)(xv + 4)  = *(const float4*)(s + 4);
      *(float4*)(xv + 8)  = *(const float4*)(s + 8);
      *(float4*)(xv + 12) = *(const float4*)(s + 12);
    }
    half8 hh[2], hl[2];
#pragma unroll
    for (int q = 0; q < 2; q++)
#pragma unroll
      for (int i = 0; i < 8; i++) {
        float x = xv[q * 8 + i];
        f16 h = (f16)x;
        hh[q][i] = h;
        hl[q][i] = (f16)(x - (float)h);
      }
    *(half8*)(Ahi + swz(r, (tid & 3) * 2 + 0)) = hh[0];
    *(half8*)(Ahi + swz(r, (tid & 3) * 2 + 1)) = hh[1];
    *(half8*)(Alo + swz(r, (tid & 3) * 2 + 0)) = hl[0];
    *(half8*)(Alo + swz(r, (tid & 3) * 2 + 1)) = hl[1];
    // stage gw0T tile [32][64]
    int nb = tid >> 3, chb = tid & 7;
    half8 bh = *(const half8*)(g0hi + (size_t)nb * 576 + kt * 64 + chb * 8);
    half8 bl = *(const half8*)(g0lo + (size_t)nb * 576 + kt * 64 + chb * 8);
    *(half8*)(Bhi + swz(nb, chb)) = bh;
    *(half8*)(Blo + swz(nb, chb)) = bl;
    __syncthreads();
    // compute: wave handles rows wave*16..+16
#pragma unroll
    for (int ks = 0; ks < 2; ks++) {
      int arow = wave * 16 + (lane & 15);
      int ch = ks * 4 + (lane >> 4);
      half8 ah = *(const half8*)(Ahi + swz(arow, ch));
      half8 al = *(const half8*)(Alo + swz(arow, ch));
#pragma unroll
      for (int n = 0; n < 2; n++) {
        int brow = n * 16 + (lane & 15);
        half8 wh = *(const half8*)(Bhi + swz(brow, ch));
        half8 wl = *(const half8*)(Blo + swz(brow, ch));
        acc[n] = __builtin_amdgcn_mfma_f32_16x16x32_f16(ah, wh, acc[n], 0, 0, 0);
        acc[n] = __builtin_amdgcn_mfma_f32_16x16x32_f16(al, wh, acc[n], 0, 0, 0);
        acc[n] = __builtin_amdgcn_mfma_f32_16x16x32_f16(ah, wl, acc[n], 0, 0, 0);
      }
    }
  }
  // h1 = elu(.) -> LDS
#pragma unroll
  for (int n = 0; n < 2; n++)
#pragma unroll
    for (int i = 0; i < 4; i++) {
      int row = wave * 16 + (lane >> 4) * 4 + i;
      int col = n * 16 + (lane & 15);
      h_lds[row][col] = elu_f(acc[n][i]);
    }
  __syncthreads();
  // layer 1: h2 = elu(h1 @ gw1 + gb1)
  {
    int row = tid & 63, q = tid >> 6;
    float a2[8];
#pragma unroll
    for (int o = 0; o < 8; o++) a2[o] = gb1[q * 8 + o];
    for (int j = 0; j < 32; j++) {
      float v = h_lds[row][j];
#pragma unroll
      for (int o = 0; o < 8; o++) a2[o] = fmaf(v, gw1[j * 32 + q * 8 + o], a2[o]);
    }
    __syncthreads();
#pragma unroll
    for (int o = 0; o < 8; o++) h_lds[row][q * 8 + o] = elu_f(a2[o]);
  }
  __syncthreads();
  // layer 2 + softmax (wave 0 only; 64 rows)
  if (wave == 0) {
    float lg[6];
#pragma unroll
    for (int e = 0; e < 6; e++) lg[e] = gb2[e];
    for (int j = 0; j < 32; j++) {
      float v = h_lds[lane][j];
#pragma unroll
      for (int e = 0; e < 6; e++) lg[e] = fmaf(v, gw2[j * 6 + e], lg[e]);
    }
    float mx = lg[0];
#pragma unroll
    for (int e = 1; e < 6; e++) mx = fmaxf(mx, lg[e]);
    float s = 0.f, pc[6];
#pragma unroll
    for (int e = 0; e < 6; e++) { pc[e] = __expf(lg[e] - mx); s += pc[e]; }
    float inv = 1.0f / s;
#pragma unroll
    for (int e = 0; e < 6; e++) coefT[e * B_ + b0 + lane] = pc[e] * inv;
  }
}

// ---------------- main mixed-expert GEMM -----------------------------------------
// C[b, k] = sum_e coef[b,e] * ( X[b,:J] @ Wt[e][k][:J]^T + bias[e][k] )
// Restructured: A-tile scaled by coef at LDS-stage time -> single accumulator;
// bias term folded into accumulator init.
// MODE 0: out_act[b*ASTR + k] = f16(elu(C));  MODE 1: out_f32[b*512+k] = C + 0.05*eps
template <int J, int KOUT, int MODE>
__global__ __launch_bounds__(256, 2) void moe_gemm(
    const f16* __restrict__ act, const f16* __restrict__ wt,
    const float* __restrict__ coefT, const float* __restrict__ bias,
    f16* __restrict__ out_act, float* __restrict__ out_f32) {
  constexpr int NSUB = J / 64;
  constexpr int NT = E_ * NSUB;
  constexpr int NTILE = KOUT / 128;
  __shared__ __align__(16) char sm[32768];
  char* As = sm;
  char* Bs = sm + 16384;

  const int tid = threadIdx.x;
  const int lane = tid & 63;
  const int wave = tid >> 6;
  const int wr = wave >> 1, wc = wave & 1;
  // XCD-bijective block swizzle (grid % 8 == 0)
  const int nwg = gridDim.x;
  const int cpx = nwg >> 3;
  const int bid = (blockIdx.x & 7) * cpx + (blockIdx.x >> 3);
  const int b0 = (bid / NTILE) * 128;
  const int n0 = (bid % NTILE) * 128;

  const int srow = tid >> 3;   // staging row (+i*32)
  const int sch  = tid & 7;    // staging 16B chunk

  uint4 aReg[4], bReg[4];
  auto loadTile = [&](int e, int ks) {
    const f16* aSrc = act + (size_t)(b0 + srow) * ASTR + ks * 64 + sch * 8;
    const f16* bSrc = wt + ((size_t)e * KOUT + n0 + srow) * J + ks * 64 + sch * 8;
#pragma unroll
    for (int i = 0; i < 4; i++) {
      aReg[i] = *(const uint4*)(aSrc + (size_t)(i * 32) * ASTR);
      bReg[i] = *(const uint4*)(bSrc + (size_t)(i * 32) * J);
    }
  };
  loadTile(0, 0);

  // coef for staging rows, expert 0
  float cf[4];
#pragma unroll
  for (int i = 0; i < 4; i++) cf[i] = coefT[b0 + srow + i * 32];

  // acc init = bias mix: acc[m][n][i] = sum_e coef[e][row] * bias[e][col]
  f32x4 acc[4][4];
#pragma unroll
  for (int m = 0; m < 4; m++)
#pragma unroll
    for (int n = 0; n < 4; n++) {
      f32x4 z = {0.f, 0.f, 0.f, 0.f};
      acc[m][n] = z;
    }
#pragma unroll
  for (int e = 0; e < E_; e++) {
    float bv[4];
#pragma unroll
    for (int n = 0; n < 4; n++)
      bv[n] = bias[e * KOUT + n0 + wc * 64 + n * 16 + (lane & 15)];
#pragma unroll
    for (int m = 0; m < 4; m++)
#pragma unroll
      for (int i = 0; i < 4; i++) {
        float cv = coefT[e * B_ + b0 + wr * 64 + m * 16 + (lane >> 4) * 4 + i];
#pragma unroll
        for (int n = 0; n < 4; n++) acc[m][n][i] = fmaf(cv, bv[n], acc[m][n][i]);
      }
  }

  int eW = 0, ksW = 0;  // expert/k-sub of tile being staged+computed this iter
  int eL = 0, ksL = 0;  // expert/k-sub of last loaded tile
  for (int kt = 0; kt < NT; ++kt) {
    __syncthreads();
    // stage: A scaled by coef (expert mixing via MFMA accumulation), B raw
#pragma unroll
    for (int i = 0; i < 4; i++) {
      int row = srow + i * 32;
      half8 av = *(half8*)&aReg[i];
      *(half8*)(As + swz(row, sch)) = av * splat8((f16)cf[i]);
      *(uint4*)(Bs + swz(row, sch)) = bReg[i];
    }
    __syncthreads();
    // prefetch next tile into regs (overlaps MFMA)
    ksL++;
    if (ksL == NSUB) { ksL = 0; eL++; }
    if (kt + 1 < NT) loadTile(eL, ksL);
    // advance staging expert; reload coef early for next iteration
    ksW++;
    if (ksW == NSUB) {
      ksW = 0; eW++;
      if (eW < E_) {
#pragma unroll
        for (int i = 0; i < 4; i++) cf[i] = coefT[eW * B_ + b0 + srow + i * 32];
      }
    }
#pragma unroll
    for (int ks2 = 0; ks2 < 2; ++ks2) {
      half8 af[4], bf[4];
#pragma unroll
      for (int m = 0; m < 4; m++) {
        int row = wr * 64 + m * 16 + (lane & 15);
        af[m] = *(const half8*)(As + swz(row, ks2 * 4 + (lane >> 4)));
      }
#pragma unroll
      for (int n = 0; n < 4; n++) {
        int rn = wc * 64 + n * 16 + (lane & 15);
        bf[n] = *(const half8*)(Bs + swz(rn, ks2 * 4 + (lane >> 4)));
      }
#pragma unroll
      for (int m = 0; m < 4; m++)
#pragma unroll
        for (int n = 0; n < 4; n++)
          acc[m][n] = __builtin_amdgcn_mfma_f32_16x16x32_f16(af[m], bf[n], acc[m][n], 0, 0, 0);
    }
  }
  // epilogue (bias+coef already folded in)
#pragma unroll
  for (int m = 0; m < 4; m++)
#pragma unroll
    for (int n = 0; n < 4; n++)
#pragma unroll
      for (int i = 0; i < 4; i++) {
        int row = b0 + wr * 64 + m * 16 + (lane >> 4) * 4 + i;
        int col = n0 + wc * 64 + n * 16 + (lane & 15);
        float x = acc[m][n][i];
        if (MODE == 0) {
          out_act[(size_t)row * ASTR + col] = (f16)elu_f(x);
        } else {
          u32 idx = (u32)row * AOUT + col;
          out_f32[idx] = fmaf(0.05f, jax_eps(idx), x);
        }
      }
}

// ---------------- launch ----------------------------------------------------------
extern "C" void kernel_launch(void* const* d_in, const int* in_sizes, int n_in,
                              void* d_out, int out_size, void* d_ws, size_t ws_size,
                              hipStream_t stream) {
  (void)in_sizes; (void)n_in; (void)out_size; (void)ws_size;
  const float* state  = (const float*)d_in[0];
  const float* latent = (const float*)d_in[1];
  const float* w0 = (const float*)d_in[2];
  const float* b0 = (const float*)d_in[3];
  const float* w1 = (const float*)d_in[4];
  const float* b1 = (const float*)d_in[5];
  const float* w2 = (const float*)d_in[6];
  const float* b2 = (const float*)d_in[7];
  const float* w3 = (const float*)d_in[8];
  const float* b3 = (const float*)d_in[9];
  const float* gw0 = (const float*)d_in[10];
  const float* gb0 = (const float*)d_in[11];
  const float* gw1 = (const float*)d_in[12];
  const float* gb1 = (const float*)d_in[13];
  const float* gw2 = (const float*)d_in[14];
  const float* gb2 = (const float*)d_in[15];

  char* ws = (char*)d_ws;
  size_t off = 0;
  float* coefT = (float*)(ws + off); off += (size_t)E_ * B_ * 4;
  f16* actA = (f16*)(ws + off); off += (size_t)B_ * ASTR * 2;
  f16* actB = (f16*)(ws + off); off += (size_t)B_ * ASTR * 2;
  f16* wt0 = (f16*)(ws + off); off += (size_t)E_ * 1024 * 576 * 2;
  f16* wt1 = (f16*)(ws + off); off += (size_t)E_ * 1024 * 1088 * 2;
  f16* wt2 = (f16*)(ws + off); off += (size_t)E_ * 1024 * 1088 * 2;
  f16* wt3 = (f16*)(ws + off); off += (size_t)E_ * 512 * 1088 * 2;
  f16* g0hi = (f16*)(ws + off); off += 32 * 576 * 2;
  f16* g0lo = (f16*)(ws + off); off += 32 * 576 * 2;

  prep_act<<<4608, 256, 0, stream>>>(state, latent, actA, actB);
  prep_gw0<<<72, 256, 0, stream>>>(gw0, g0hi, g0lo);
  transpose_w<<<6 * 9 * 16, 256, 0, stream>>>(w0, wt0, 576, 1024);
  transpose_w<<<6 * 17 * 16, 256, 0, stream>>>(w1, wt1, 1088, 1024);
  transpose_w<<<6 * 17 * 16, 256, 0, stream>>>(w2, wt2, 1088, 1024);
  transpose_w<<<6 * 17 * 8, 256, 0, stream>>>(w3, wt3, 1088, 512);
  gating_kernel<<<256, 256, 0, stream>>>(state, latent, g0hi, g0lo, gb0, gw1, gb1,
                                         gw2, gb2, coefT);
  moe_gemm<576, 1024, 0><<<1024, 256, 0, stream>>>(actA, wt0, coefT, b0, actB, nullptr);
  moe_gemm<1088, 1024, 0><<<1024, 256, 0, stream>>>(actB, wt1, coefT, b1, actA, nullptr);
  moe_gemm<1088, 1024, 0><<<1024, 256, 0, stream>>>(actA, wt2, coefT, b2, actB, nullptr);
  moe_gemm<1088, 512, 1><<<512, 256, 0, stream>>>(actB, wt3, coefT, b3, nullptr, (float*)d_out);
}

// Round 3
// 738.002 us; speedup vs baseline: 3.7071x; 2.1646x over previous
//
#include <hip/hip_runtime.h>

typedef _Float16 f16;
typedef _Float16 half8 __attribute__((ext_vector_type(8)));
typedef float f32x4 __attribute__((ext_vector_type(4)));
typedef unsigned int u32;

#define B_    16384
#define E_    6
#define ASTR  1088     // row stride of activation buffers (f16 elements)
#define AOUT  512

// XOR swizzle: tile rows are 64 f16 = 128B = 8 chunks of 16B.
// Physical chunk = logical chunk ^ (row & 7).
// LDS image is produced PRE-SWIZZLED by global_load_lds (source addr carries the
// inverse permutation = same involution); ds_reads apply swz() to recover.
__device__ __forceinline__ u32 swz(u32 row, u32 ch) {
  return row * 128u + ((ch ^ (row & 7u)) * 16u);
}

__device__ __forceinline__ float elu_f(float x) {
  return x > 0.f ? x : (__expf(x) - 1.f);
}

__device__ __forceinline__ half8 splat8(f16 s) {
  half8 v = {s, s, s, s, s, s, s, s};
  return v;
}

// async global->LDS, 16B per lane. LDS base must be wave-uniform.
__device__ __forceinline__ void gload16(const f16* g, char* l) {
  __builtin_amdgcn_global_load_lds(
      (const __attribute__((address_space(1))) void*)g,
      (__attribute__((address_space(3))) void*)l, 16, 0, 0);
}

// Reproduce jax.random.normal(jax.random.key(42), (B,512), f32)[idx]
// threefry2x32, partitionable mode: bits[idx] = x0^x1 of block (hi=0, lo=idx), key=(0,42)
// then uniform(nextafter(-1,0), 1) -> sqrt(2)*erfinv (XLA/Giles f32 polynomial)
__device__ __forceinline__ float jax_eps(u32 idx) {
  const u32 k0 = 0u, k1 = 42u;
  const u32 k2 = k0 ^ k1 ^ 0x1BD11BDAu;
  u32 x0 = 0u + k0, x1 = idx + k1;
#define TFR(r) { x0 += x1; x1 = (x1 << (r)) | (x1 >> (32 - (r))); x1 ^= x0; }
  TFR(13) TFR(15) TFR(26) TFR(6)   x0 += k1; x1 += k2 + 1u;
  TFR(17) TFR(29) TFR(16) TFR(24)  x0 += k2; x1 += k0 + 2u;
  TFR(13) TFR(15) TFR(26) TFR(6)   x0 += k0; x1 += k1 + 3u;
  TFR(17) TFR(29) TFR(16) TFR(24)  x0 += k1; x1 += k2 + 4u;
  TFR(13) TFR(15) TFR(26) TFR(6)   x0 += k2; x1 += k0 + 5u;
#undef TFR
  u32 bits = x0 ^ x1;
  float f = __uint_as_float(0x3f800000u | (bits >> 9)) - 1.0f;  // [0,1)
  const float lo = -0.99999994f;                                 // nextafter(-1,0)
  float u = fmaxf(lo, fmaf(f, 2.0f, lo));                        // (maxval-minval) rounds to 2.0f
  float w = -__logf(fmaf(-u, u, 1.0f));
  float p;
  if (w < 5.0f) {
    w -= 2.5f;
    p = 2.81022636e-08f;
    p = fmaf(p, w, 3.43273939e-07f);
    p = fmaf(p, w, -3.5233877e-06f);
    p = fmaf(p, w, -4.39150654e-06f);
    p = fmaf(p, w, 0.00021858087f);
    p = fmaf(p, w, -0.00125372503f);
    p = fmaf(p, w, -0.00417768164f);
    p = fmaf(p, w, 0.246640727f);
    p = fmaf(p, w, 1.50140941f);
  } else {
    w = __fsqrt_rn(w) - 3.0f;
    p = -0.000200214257f;
    p = fmaf(p, w, 0.000100950558f);
    p = fmaf(p, w, 0.00134934322f);
    p = fmaf(p, w, -0.00367342844f);
    p = fmaf(p, w, 0.00573950773f);
    p = fmaf(p, w, -0.0076224613f);
    p = fmaf(p, w, 0.00943887047f);
    p = fmaf(p, w, 1.00167406f);
    p = fmaf(p, w, 2.83297682f);
  }
  return 1.41421356f * p * u;
}

// ---------------- prep: activations (state+latent -> f16 buffers) ----------------
__global__ void prep_act(const float* __restrict__ state, const float* __restrict__ latent,
                         f16* __restrict__ actA, f16* __restrict__ actB) {
  const u32 NS = (B_ * 512u) / 8u;   // 1048576
  const u32 NL = (B_ * 64u) / 8u;    // 131072
  u32 i = blockIdx.x * 256u + threadIdx.x;
  if (i < NS) {
    u32 e = i * 8u;
    u32 b = e >> 9, c = e & 511u;
    float4 v0 = *(const float4*)(state + e);
    float4 v1 = *(const float4*)(state + e + 4);
    half8 h;
    h[0]=(f16)v0.x; h[1]=(f16)v0.y; h[2]=(f16)v0.z; h[3]=(f16)v0.w;
    h[4]=(f16)v1.x; h[5]=(f16)v1.y; h[6]=(f16)v1.z; h[7]=(f16)v1.w;
    *(half8*)(actA + (size_t)b * ASTR + c) = h;
  } else if (i < NS + NL) {
    u32 e = (i - NS) * 8u;
    u32 b = e >> 6, c = e & 63u;
    float4 v0 = *(const float4*)(latent + e);
    float4 v1 = *(const float4*)(latent + e + 4);
    half8 h;
    h[0]=(f16)v0.x; h[1]=(f16)v0.y; h[2]=(f16)v0.z; h[3]=(f16)v0.w;
    h[4]=(f16)v1.x; h[5]=(f16)v1.y; h[6]=(f16)v1.z; h[7]=(f16)v1.w;
    *(half8*)(actA + (size_t)b * ASTR + 512 + c) = h;   // layer0 input cols 512..575
    *(half8*)(actA + (size_t)b * ASTR + 1024 + c) = h;  // layer2 input cols 1024..1087
    *(half8*)(actB + (size_t)b * ASTR + 1024 + c) = h;  // layer1/3 input cols 1024..1087
  }
}

// ---------------- prep: gating W0 transpose + hi/lo split ----------------
__global__ void prep_gw0(const float* __restrict__ gw0, f16* __restrict__ g0hi,
                         f16* __restrict__ g0lo) {
  int i = blockIdx.x * 256 + threadIdx.x;  // over 32*576
  if (i < 32 * 576) {
    int n = i / 576, j = i % 576;
    float v = gw0[j * 32 + n];
    f16 h = (f16)v;
    g0hi[i] = h;
    g0lo[i] = (f16)(v - (float)h);
  }
}

// ---------------- prep: expert-weight transpose+convert w[e][j][k] -> wt[e][k][j] f16 ---
__global__ void transpose_w(const float* __restrict__ w, f16* __restrict__ wt,
                            int J, int K) {
  __shared__ float t[64][65];
  int tiles_j = J >> 6, tiles_k = K >> 6;
  int per_e = tiles_j * tiles_k;
  int bid = blockIdx.x;
  int e = bid / per_e, rem = bid % per_e;
  int jt = rem / tiles_k, kt = rem % tiles_k;
  int tid = threadIdx.x;
  int r = tid >> 2, c0 = (tid & 3) << 4;
  const float* src = w + ((size_t)e * J + (size_t)jt * 64 + r) * K + (size_t)kt * 64 + c0;
  float4 v0 = *(const float4*)(src);
  float4 v1 = *(const float4*)(src + 4);
  float4 v2 = *(const float4*)(src + 8);
  float4 v3 = *(const float4*)(src + 12);
  t[r][c0+0]=v0.x;  t[r][c0+1]=v0.y;  t[r][c0+2]=v0.z;  t[r][c0+3]=v0.w;
  t[r][c0+4]=v1.x;  t[r][c0+5]=v1.y;  t[r][c0+6]=v1.z;  t[r][c0+7]=v1.w;
  t[r][c0+8]=v2.x;  t[r][c0+9]=v2.y;  t[r][c0+10]=v2.z; t[r][c0+11]=v2.w;
  t[r][c0+12]=v3.x; t[r][c0+13]=v3.y; t[r][c0+14]=v3.z; t[r][c0+15]=v3.w;
  __syncthreads();
  int kr = tid >> 2, jq = (tid & 3) << 4;
  half8 p0, p1;
#pragma unroll
  for (int m = 0; m < 8; m++) {
    p0[m] = (f16)t[jq + m][kr];
    p1[m] = (f16)t[jq + 8 + m][kr];
  }
  f16* dst = wt + ((size_t)e * K + (size_t)kt * 64 + kr) * J + (size_t)jt * 64 + jq;
  *(half8*)(dst) = p0;
  *(half8*)(dst + 8) = p1;
}

// ---------------- gating MLP: coefT[e][b] = softmax over experts -----------------
// layer0 via split-f16 MFMA (f32-accurate), layers 1-2 tiny f32 VALU
__global__ __launch_bounds__(256) void gating_kernel(
    const float* __restrict__ state, const float* __restrict__ latent,
    const f16* __restrict__ g0hi, const f16* __restrict__ g0lo,
    const float* __restrict__ gb0, const float* __restrict__ gw1,
    const float* __restrict__ gb1, const float* __restrict__ gw2,
    const float* __restrict__ gb2, float* __restrict__ coefT) {
  __shared__ __align__(16) char sm[24576];  // Ahi 8K | Alo 8K | Bhi 4K | Blo 4K
  __shared__ float h_lds[64][33];
  char* Ahi = sm;
  char* Alo = sm + 8192;
  char* Bhi = sm + 16384;
  char* Blo = sm + 20480;
  const int tid = threadIdx.x, lane = tid & 63, wave = tid >> 6;
  const int b0 = blockIdx.x * 64;

  f32x4 acc[2];
#pragma unroll
  for (int n = 0; n < 2; n++) {
    float v = gb0[n * 16 + (lane & 15)];
    f32x4 t = {v, v, v, v};
    acc[n] = t;
  }

  for (int kt = 0; kt < 9; ++kt) {
    __syncthreads();
    // stage Xc tile [64][64]: hi/lo split
    int r = tid >> 2, cq = (tid & 3) << 4;
    float xv[16];
    if (kt < 8) {
      const float* s = state + (size_t)(b0 + r) * 512 + kt * 64 + cq;
      *(float4*)(xv)      = *(const float4*)(s);
      *(float4*)(xv + 4)  = *(const float4*)(s + 4);
      *(float4*)(xv + 8)  = *(const float4*)(s + 8);
      *(float4*)(xv + 12) = *(const float4*)(s + 12);
    } else {
      const float* s = latent + (size_t)(b0 + r) * 64 + cq;
      *(float4*)(xv)      = *(const float4*)(s);
      *(float4*)(xv + 4)  = *(const float4*)(s + 4);
      *(float4*)(xv + 8)  = *(const float4*)(s + 8);
      *(float4*)(xv + 12) = *(const float4*)(s + 12);
    }
    half8 hh[2], hl[2];
#pragma unroll
    for (int q = 0; q < 2; q++)
#pragma unroll
      for (int i = 0; i < 8; i++) {
        float x = xv[q * 8 + i];
        f16 h = (f16)x;
        hh[q][i] = h;
        hl[q][i] = (f16)(x - (float)h);
      }
    *(half8*)(Ahi + swz(r, (tid & 3) * 2 + 0)) = hh[0];
    *(half8*)(Ahi + swz(r, (tid & 3) * 2 + 1)) = hh[1];
    *(half8*)(Alo + swz(r, (tid & 3) * 2 + 0)) = hl[0];
    *(half8*)(Alo + swz(r, (tid & 3) * 2 + 1)) = hl[1];
    // stage gw0T tile [32][64]
    int nb = tid >> 3, chb = tid & 7;
    half8 bh = *(const half8*)(g0hi + (size_t)nb * 576 + kt * 64 + chb * 8);
    half8 bl = *(const half8*)(g0lo + (size_t)nb * 576 + kt * 64 + chb * 8);
    *(half8*)(Bhi + swz(nb, chb)) = bh;
    *(half8*)(Blo + swz(nb, chb)) = bl;
    __syncthreads();
    // compute: wave handles rows wave*16..+16
#pragma unroll
    for (int ks = 0; ks < 2; ks++) {
      int arow = wave * 16 + (lane & 15);
      int ch = ks * 4 + (lane >> 4);
      half8 ah = *(const half8*)(Ahi + swz(arow, ch));
      half8 al = *(const half8*)(Alo + swz(arow, ch));
#pragma unroll
      for (int n = 0; n < 2; n++) {
        int brow = n * 16 + (lane & 15);
        half8 wh = *(const half8*)(Bhi + swz(brow, ch));
        half8 wl = *(const half8*)(Blo + swz(brow, ch));
        acc[n] = __builtin_amdgcn_mfma_f32_16x16x32_f16(ah, wh, acc[n], 0, 0, 0);
        acc[n] = __builtin_amdgcn_mfma_f32_16x16x32_f16(al, wh, acc[n], 0, 0, 0);
        acc[n] = __builtin_amdgcn_mfma_f32_16x16x32_f16(ah, wl, acc[n], 0, 0, 0);
      }
    }
  }
  // h1 = elu(.) -> LDS
#pragma unroll
  for (int n = 0; n < 2; n++)
#pragma unroll
    for (int i = 0; i < 4; i++) {
      int row = wave * 16 + (lane >> 4) * 4 + i;
      int col = n * 16 + (lane & 15);
      h_lds[row][col] = elu_f(acc[n][i]);
    }
  __syncthreads();
  // layer 1: h2 = elu(h1 @ gw1 + gb1)
  {
    int row = tid & 63, q = tid >> 6;
    float a2[8];
#pragma unroll
    for (int o = 0; o < 8; o++) a2[o] = gb1[q * 8 + o];
    for (int j = 0; j < 32; j++) {
      float v = h_lds[row][j];
#pragma unroll
      for (int o = 0; o < 8; o++) a2[o] = fmaf(v, gw1[j * 32 + q * 8 + o], a2[o]);
    }
    __syncthreads();
#pragma unroll
    for (int o = 0; o < 8; o++) h_lds[row][q * 8 + o] = elu_f(a2[o]);
  }
  __syncthreads();
  // layer 2 + softmax (wave 0 only; 64 rows)
  if (wave == 0) {
    float lg[6];
#pragma unroll
    for (int e = 0; e < 6; e++) lg[e] = gb2[e];
    for (int j = 0; j < 32; j++) {
      float v = h_lds[lane][j];
#pragma unroll
      for (int e = 0; e < 6; e++) lg[e] = fmaf(v, gw2[j * 6 + e], lg[e]);
    }
    float mx = lg[0];
#pragma unroll
    for (int e = 1; e < 6; e++) mx = fmaxf(mx, lg[e]);
    float s = 0.f, pc[6];
#pragma unroll
    for (int e = 0; e < 6; e++) { pc[e] = __expf(lg[e] - mx); s += pc[e]; }
    float inv = 1.0f / s;
#pragma unroll
    for (int e = 0; e < 6; e++) coefT[e * B_ + b0 + lane] = pc[e] * inv;
  }
}

// ---------------- main mixed-expert GEMM -----------------------------------------
// C[b, k] = sum_e coef[b,e] * ( X[b,:J] @ Wt[e][k][:J]^T + bias[e][k] )
// ks-outer / expert-inner(unrolled): A staged ONCE per ks via global_load_lds,
// coef scaling applied to A-fragments in registers, bias mix folded into acc init.
// Both tiles staged with global_load_lds (16B) + source-side XOR swizzle.
// MODE 0: out_act[b*ASTR + k] = f16(elu(C));  MODE 1: out_f32[b*512+k] = C + 0.05*eps
template <int J, int KOUT, int MODE>
__global__ __launch_bounds__(256, 2) void moe_gemm(
    const f16* __restrict__ act, const f16* __restrict__ wt,
    const float* __restrict__ coefT, const float* __restrict__ bias,
    f16* __restrict__ out_act, float* __restrict__ out_f32) {
  constexpr int NSUB = J / 64;
  constexpr int NTILE = KOUT / 128;
  __shared__ __align__(16) char sm[49152];  // As 16K | Bs0 16K | Bs1 16K
  char* As  = sm;
  char* Bs0 = sm + 16384;
  char* Bs1 = sm + 32768;

  const int tid = threadIdx.x;
  const int lane = tid & 63;
  const int wv = tid >> 6;
  const int wr = wv >> 1, wc = wv & 1;
  // XCD-bijective block swizzle (grid % 8 == 0)
  const int nwg = gridDim.x;
  const int cpx = nwg >> 3;
  const int bid = (blockIdx.x & 7) * cpx + (blockIdx.x >> 3);
  const int b0 = (bid / NTILE) * 128;
  const int n0 = (bid % NTILE) * 128;

  // staging geometry: wave wv, issue i covers tile rows wv*32+i*8 .. +7, 128B each.
  // source column pre-swizzled so linear LDS image matches swz() reads.
  int srow[4], scol[4];
#pragma unroll
  for (int i = 0; i < 4; i++) {
    int r = wv * 32 + i * 8 + (lane >> 3);
    srow[i] = r;
    scol[i] = ((lane & 7) ^ (r & 7)) * 8;
  }

  auto stageA = [&](int ks) {
#pragma unroll
    for (int i = 0; i < 4; i++)
      gload16(act + (size_t)(b0 + srow[i]) * ASTR + ks * 64 + scol[i],
              As + (wv * 4 + i) * 1024);
  };
  auto stageB = [&](int e, int ks, char* Bs) {
    const f16* wb = wt + (size_t)e * KOUT * J;
#pragma unroll
    for (int i = 0; i < 4; i++)
      gload16(wb + (size_t)(n0 + srow[i]) * J + ks * 64 + scol[i],
              Bs + (wv * 4 + i) * 1024);
  };

  stageA(0);
  stageB(0, 0, Bs0);

  // per-A-fragment-row coef, all experts (compile-time indexed in unrolled loops)
  f16 cfh[E_][4];
#pragma unroll
  for (int e = 0; e < E_; e++)
#pragma unroll
    for (int m = 0; m < 4; m++)
      cfh[e][m] = (f16)coefT[e * B_ + b0 + wr * 64 + m * 16 + (lane & 15)];

  // acc init = bias mix: acc[m][n][i] = sum_e coef[e][row] * bias[e][col]
  f32x4 acc[4][4];
#pragma unroll
  for (int m = 0; m < 4; m++)
#pragma unroll
    for (int n = 0; n < 4; n++) {
      f32x4 z = {0.f, 0.f, 0.f, 0.f};
      acc[m][n] = z;
    }
#pragma unroll
  for (int e = 0; e < E_; e++) {
    float bv[4];
#pragma unroll
    for (int n = 0; n < 4; n++)
      bv[n] = bias[e * KOUT + n0 + wc * 64 + n * 16 + (lane & 15)];
#pragma unroll
    for (int m = 0; m < 4; m++)
#pragma unroll
      for (int i = 0; i < 4; i++) {
        float cv = coefT[e * B_ + b0 + wr * 64 + m * 16 + (lane >> 4) * 4 + i];
#pragma unroll
        for (int n = 0; n < 4; n++) acc[m][n][i] = fmaf(cv, bv[n], acc[m][n][i]);
      }
  }

  half8 afr[2][4];  // raw A fragments for current ks (persist across experts)

  for (int ks = 0; ks < NSUB; ++ks) {
#pragma unroll
    for (int e = 0; e < E_; ++e) {
      __syncthreads();  // staged tiles for this iter are resident; prev reads done
      char* Bcur = (e & 1) ? Bs1 : Bs0;
      char* Bnxt = (e & 1) ? Bs0 : Bs1;
      // issue next-tile stages (drain at next barrier; latency hides under MFMA)
      if (e < E_ - 1) {
        stageB(e + 1, ks, Bnxt);
      } else if (ks + 1 < NSUB) {
        stageB(0, ks + 1, Bnxt);
        stageA(ks + 1);  // As last read 5 barriers ago -> safe to overwrite
      }
      if (e == 0) {
        // load raw A fragments for this ks once
#pragma unroll
        for (int h = 0; h < 2; h++)
#pragma unroll
          for (int m = 0; m < 4; m++) {
            int row = wr * 64 + m * 16 + (lane & 15);
            afr[h][m] = *(const half8*)(As + swz(row, h * 4 + (lane >> 4)));
          }
      }
#pragma unroll
      for (int h = 0; h < 2; h++) {
        half8 bf[4], afs[4];
#pragma unroll
        for (int n = 0; n < 4; n++) {
          int rn = wc * 64 + n * 16 + (lane & 15);
          bf[n] = *(const half8*)(Bcur + swz(rn, h * 4 + (lane >> 4)));
        }
#pragma unroll
        for (int m = 0; m < 4; m++) afs[m] = afr[h][m] * splat8(cfh[e][m]);
#pragma unroll
        for (int m = 0; m < 4; m++)
#pragma unroll
          for (int n = 0; n < 4; n++)
            acc[m][n] = __builtin_amdgcn_mfma_f32_16x16x32_f16(afs[m], bf[n], acc[m][n], 0, 0, 0);
      }
    }
  }
  // epilogue (bias+coef already folded in)
#pragma unroll
  for (int m = 0; m < 4; m++)
#pragma unroll
    for (int n = 0; n < 4; n++)
#pragma unroll
      for (int i = 0; i < 4; i++) {
        int row = b0 + wr * 64 + m * 16 + (lane >> 4) * 4 + i;
        int col = n0 + wc * 64 + n * 16 + (lane & 15);
        float x = acc[m][n][i];
        if (MODE == 0) {
          out_act[(size_t)row * ASTR + col] = (f16)elu_f(x);
        } else {
          u32 idx = (u32)row * AOUT + col;
          out_f32[idx] = fmaf(0.05f, jax_eps(idx), x);
        }
      }
}

// ---------------- launch ----------------------------------------------------------
extern "C" void kernel_launch(void* const* d_in, const int* in_sizes, int n_in,
                              void* d_out, int out_size, void* d_ws, size_t ws_size,
                              hipStream_t stream) {
  (void)in_sizes; (void)n_in; (void)out_size; (void)ws_size;
  const float* state  = (const float*)d_in[0];
  const float* latent = (const float*)d_in[1];
  const float* w0 = (const float*)d_in[2];
  const float* b0 = (const float*)d_in[3];
  const float* w1 = (const float*)d_in[4];
  const float* b1 = (const float*)d_in[5];
  const float* w2 = (const float*)d_in[6];
  const float* b2 = (const float*)d_in[7];
  const float* w3 = (const float*)d_in[8];
  const float* b3 = (const float*)d_in[9];
  const float* gw0 = (const float*)d_in[10];
  const float* gb0 = (const float*)d_in[11];
  const float* gw1 = (const float*)d_in[12];
  const float* gb1 = (const float*)d_in[13];
  const float* gw2 = (const float*)d_in[14];
  const float* gb2 = (const float*)d_in[15];

  char* ws = (char*)d_ws;
  size_t off = 0;
  float* coefT = (float*)(ws + off); off += (size_t)E_ * B_ * 4;
  f16* actA = (f16*)(ws + off); off += (size_t)B_ * ASTR * 2;
  f16* actB = (f16*)(ws + off); off += (size_t)B_ * ASTR * 2;
  f16* wt0 = (f16*)(ws + off); off += (size_t)E_ * 1024 * 576 * 2;
  f16* wt1 = (f16*)(ws + off); off += (size_t)E_ * 1024 * 1088 * 2;
  f16* wt2 = (f16*)(ws + off); off += (size_t)E_ * 1024 * 1088 * 2;
  f16* wt3 = (f16*)(ws + off); off += (size_t)E_ * 512 * 1088 * 2;
  f16* g0hi = (f16*)(ws + off); off += 32 * 576 * 2;
  f16* g0lo = (f16*)(ws + off); off += 32 * 576 * 2;

  prep_act<<<4608, 256, 0, stream>>>(state, latent, actA, actB);
  prep_gw0<<<72, 256, 0, stream>>>(gw0, g0hi, g0lo);
  transpose_w<<<6 * 9 * 16, 256, 0, stream>>>(w0, wt0, 576, 1024);
  transpose_w<<<6 * 17 * 16, 256, 0, stream>>>(w1, wt1, 1088, 1024);
  transpose_w<<<6 * 17 * 16, 256, 0, stream>>>(w2, wt2, 1088, 1024);
  transpose_w<<<6 * 17 * 8, 256, 0, stream>>>(w3, wt3, 1088, 512);
  gating_kernel<<<256, 256, 0, stream>>>(state, latent, g0hi, g0lo, gb0, gw1, gb1,
                                         gw2, gb2, coefT);
  moe_gemm<576, 1024, 0><<<1024, 256, 0, stream>>>(actA, wt0, coefT, b0, actB, nullptr);
  moe_gemm<1088, 1024, 0><<<1024, 256, 0, stream>>>(actB, wt1, coefT, b1, actA, nullptr);
  moe_gemm<1088, 1024, 0><<<1024, 256, 0, stream>>>(actA, wt2, coefT, b2, actB, nullptr);
  moe_gemm<1088, 512, 1><<<512, 256, 0, stream>>>(actB, wt3, coefT, b3, nullptr, (float*)d_out);
}

// Round 4
// 732.842 us; speedup vs baseline: 3.7332x; 1.0070x over previous
//
#include <hip/hip_runtime.h>

typedef _Float16 f16;
typedef _Float16 half8 __attribute__((ext_vector_type(8)));
typedef float f32x4 __attribute__((ext_vector_type(4)));
typedef unsigned int u32;

#define B_    16384
#define E_    6
#define ASTR  1088     // row stride of activation buffers (f16 elements)
#define AOUT  512

// XOR swizzle: tile rows are 64 f16 = 128B = 8 chunks of 16B.
// Physical chunk = logical chunk ^ (row & 7).
// LDS image is produced PRE-SWIZZLED by global_load_lds (source addr carries the
// inverse permutation = same involution); ds_reads apply swz() to recover.
__device__ __forceinline__ u32 swz(u32 row, u32 ch) {
  return row * 128u + ((ch ^ (row & 7u)) * 16u);
}

__device__ __forceinline__ float elu_f(float x) {
  return x > 0.f ? x : (__expf(x) - 1.f);
}

__device__ __forceinline__ half8 splat8(f16 s) {
  half8 v = {s, s, s, s, s, s, s, s};
  return v;
}

// async global->LDS, 16B per lane. LDS base must be wave-uniform.
__device__ __forceinline__ void gload16(const f16* g, char* l) {
  __builtin_amdgcn_global_load_lds(
      (const __attribute__((address_space(1))) void*)g,
      (__attribute__((address_space(3))) void*)l, 16, 0, 0);
}

// counted vmcnt wait (compile-time literal N)
#define WAITVM(N) asm volatile("s_waitcnt vmcnt(" #N ")" ::: "memory")

// Reproduce jax.random.normal(jax.random.key(42), (B,512), f32)[idx]
// threefry2x32, partitionable mode: bits[idx] = x0^x1 of block (hi=0, lo=idx), key=(0,42)
// then uniform(nextafter(-1,0), 1) -> sqrt(2)*erfinv (XLA/Giles f32 polynomial)
__device__ __forceinline__ float jax_eps(u32 idx) {
  const u32 k0 = 0u, k1 = 42u;
  const u32 k2 = k0 ^ k1 ^ 0x1BD11BDAu;
  u32 x0 = 0u + k0, x1 = idx + k1;
#define TFR(r) { x0 += x1; x1 = (x1 << (r)) | (x1 >> (32 - (r))); x1 ^= x0; }
  TFR(13) TFR(15) TFR(26) TFR(6)   x0 += k1; x1 += k2 + 1u;
  TFR(17) TFR(29) TFR(16) TFR(24)  x0 += k2; x1 += k0 + 2u;
  TFR(13) TFR(15) TFR(26) TFR(6)   x0 += k0; x1 += k1 + 3u;
  TFR(17) TFR(29) TFR(16) TFR(24)  x0 += k1; x1 += k2 + 4u;
  TFR(13) TFR(15) TFR(26) TFR(6)   x0 += k2; x1 += k0 + 5u;
#undef TFR
  u32 bits = x0 ^ x1;
  float f = __uint_as_float(0x3f800000u | (bits >> 9)) - 1.0f;  // [0,1)
  const float lo = -0.99999994f;                                 // nextafter(-1,0)
  float u = fmaxf(lo, fmaf(f, 2.0f, lo));                        // (maxval-minval) rounds to 2.0f
  float w = -__logf(fmaf(-u, u, 1.0f));
  float p;
  if (w < 5.0f) {
    w -= 2.5f;
    p = 2.81022636e-08f;
    p = fmaf(p, w, 3.43273939e-07f);
    p = fmaf(p, w, -3.5233877e-06f);
    p = fmaf(p, w, -4.39150654e-06f);
    p = fmaf(p, w, 0.00021858087f);
    p = fmaf(p, w, -0.00125372503f);
    p = fmaf(p, w, -0.00417768164f);
    p = fmaf(p, w, 0.246640727f);
    p = fmaf(p, w, 1.50140941f);
  } else {
    w = __fsqrt_rn(w) - 3.0f;
    p = -0.000200214257f;
    p = fmaf(p, w, 0.000100950558f);
    p = fmaf(p, w, 0.00134934322f);
    p = fmaf(p, w, -0.00367342844f);
    p = fmaf(p, w, 0.00573950773f);
    p = fmaf(p, w, -0.0076224613f);
    p = fmaf(p, w, 0.00943887047f);
    p = fmaf(p, w, 1.00167406f);
    p = fmaf(p, w, 2.83297682f);
  }
  return 1.41421356f * p * u;
}

// ---------------- prep: activations (state+latent -> f16 buffers) ----------------
__global__ void prep_act(const float* __restrict__ state, const float* __restrict__ latent,
                         f16* __restrict__ actA, f16* __restrict__ actB) {
  const u32 NS = (B_ * 512u) / 8u;   // 1048576
  const u32 NL = (B_ * 64u) / 8u;    // 131072
  u32 i = blockIdx.x * 256u + threadIdx.x;
  if (i < NS) {
    u32 e = i * 8u;
    u32 b = e >> 9, c = e & 511u;
    float4 v0 = *(const float4*)(state + e);
    float4 v1 = *(const float4*)(state + e + 4);
    half8 h;
    h[0]=(f16)v0.x; h[1]=(f16)v0.y; h[2]=(f16)v0.z; h[3]=(f16)v0.w;
    h[4]=(f16)v1.x; h[5]=(f16)v1.y; h[6]=(f16)v1.z; h[7]=(f16)v1.w;
    *(half8*)(actA + (size_t)b * ASTR + c) = h;
  } else if (i < NS + NL) {
    u32 e = (i - NS) * 8u;
    u32 b = e >> 6, c = e & 63u;
    float4 v0 = *(const float4*)(latent + e);
    float4 v1 = *(const float4*)(latent + e + 4);
    half8 h;
    h[0]=(f16)v0.x; h[1]=(f16)v0.y; h[2]=(f16)v0.z; h[3]=(f16)v0.w;
    h[4]=(f16)v1.x; h[5]=(f16)v1.y; h[6]=(f16)v1.z; h[7]=(f16)v1.w;
    *(half8*)(actA + (size_t)b * ASTR + 512 + c) = h;   // layer0 input cols 512..575
    *(half8*)(actA + (size_t)b * ASTR + 1024 + c) = h;  // layer2 input cols 1024..1087
    *(half8*)(actB + (size_t)b * ASTR + 1024 + c) = h;  // layer1/3 input cols 1024..1087
  }
}

// ---------------- prep: gating W0 transpose + hi/lo split ----------------
__global__ void prep_gw0(const float* __restrict__ gw0, f16* __restrict__ g0hi,
                         f16* __restrict__ g0lo) {
  int i = blockIdx.x * 256 + threadIdx.x;  // over 32*576
  if (i < 32 * 576) {
    int n = i / 576, j = i % 576;
    float v = gw0[j * 32 + n];
    f16 h = (f16)v;
    g0hi[i] = h;
    g0lo[i] = (f16)(v - (float)h);
  }
}

// ---------------- prep: expert-weight transpose+convert w[e][j][k] -> wt[e][k][j] f16 ---
__global__ void transpose_w(const float* __restrict__ w, f16* __restrict__ wt,
                            int J, int K) {
  __shared__ float t[64][65];
  int tiles_j = J >> 6, tiles_k = K >> 6;
  int per_e = tiles_j * tiles_k;
  int bid = blockIdx.x;
  int e = bid / per_e, rem = bid % per_e;
  int jt = rem / tiles_k, kt = rem % tiles_k;
  int tid = threadIdx.x;
  int r = tid >> 2, c0 = (tid & 3) << 4;
  const float* src = w + ((size_t)e * J + (size_t)jt * 64 + r) * K + (size_t)kt * 64 + c0;
  float4 v0 = *(const float4*)(src);
  float4 v1 = *(const float4*)(src + 4);
  float4 v2 = *(const float4*)(src + 8);
  float4 v3 = *(const float4*)(src + 12);
  t[r][c0+0]=v0.x;  t[r][c0+1]=v0.y;  t[r][c0+2]=v0.z;  t[r][c0+3]=v0.w;
  t[r][c0+4]=v1.x;  t[r][c0+5]=v1.y;  t[r][c0+6]=v1.z;  t[r][c0+7]=v1.w;
  t[r][c0+8]=v2.x;  t[r][c0+9]=v2.y;  t[r][c0+10]=v2.z; t[r][c0+11]=v2.w;
  t[r][c0+12]=v3.x; t[r][c0+13]=v3.y; t[r][c0+14]=v3.z; t[r][c0+15]=v3.w;
  __syncthreads();
  int kr = tid >> 2, jq = (tid & 3) << 4;
  half8 p0, p1;
#pragma unroll
  for (int m = 0; m < 8; m++) {
    p0[m] = (f16)t[jq + m][kr];
    p1[m] = (f16)t[jq + 8 + m][kr];
  }
  f16* dst = wt + ((size_t)e * K + (size_t)kt * 64 + kr) * J + (size_t)jt * 64 + jq;
  *(half8*)(dst) = p0;
  *(half8*)(dst + 8) = p1;
}

// ---------------- gating MLP: coefT[e][b] = softmax over experts -----------------
// layer0 via split-f16 MFMA (f32-accurate), layers 1-2 tiny f32 VALU
__global__ __launch_bounds__(256) void gating_kernel(
    const float* __restrict__ state, const float* __restrict__ latent,
    const f16* __restrict__ g0hi, const f16* __restrict__ g0lo,
    const float* __restrict__ gb0, const float* __restrict__ gw1,
    const float* __restrict__ gb1, const float* __restrict__ gw2,
    const float* __restrict__ gb2, float* __restrict__ coefT) {
  __shared__ __align__(16) char sm[24576];  // Ahi 8K | Alo 8K | Bhi 4K | Blo 4K
  __shared__ float h_lds[64][33];
  char* Ahi = sm;
  char* Alo = sm + 8192;
  char* Bhi = sm + 16384;
  char* Blo = sm + 20480;
  const int tid = threadIdx.x, lane = tid & 63, wave = tid >> 6;
  const int b0 = blockIdx.x * 64;

  f32x4 acc[2];
#pragma unroll
  for (int n = 0; n < 2; n++) {
    float v = gb0[n * 16 + (lane & 15)];
    f32x4 t = {v, v, v, v};
    acc[n] = t;
  }

  for (int kt = 0; kt < 9; ++kt) {
    __syncthreads();
    // stage Xc tile [64][64]: hi/lo split
    int r = tid >> 2, cq = (tid & 3) << 4;
    float xv[16];
    if (kt < 8) {
      const float* s = state + (size_t)(b0 + r) * 512 + kt * 64 + cq;
      *(float4*)(xv)      = *(const float4*)(s);
      *(float4*)(xv + 4)  = *(const float4*)(s + 4);
      *(float4*)(xv + 8)  = *(const float4*)(s + 8);
      *(float4*)(xv + 12) = *(const float4*)(s + 12);
    } else {
      const float* s = latent + (size_t)(b0 + r) * 64 + cq;
      *(float4*)(xv)      = *(const float4*)(s);
      *(float4*)(xv + 4)  = *(const float4*)(s + 4);
      *(float4*)(xv + 8)  = *(const float4*)(s + 8);
      *(float4*)(xv + 12) = *(const float4*)(s + 12);
    }
    half8 hh[2], hl[2];
#pragma unroll
    for (int q = 0; q < 2; q++)
#pragma unroll
      for (int i = 0; i < 8; i++) {
        float x = xv[q * 8 + i];
        f16 h = (f16)x;
        hh[q][i] = h;
        hl[q][i] = (f16)(x - (float)h);
      }
    *(half8*)(Ahi + swz(r, (tid & 3) * 2 + 0)) = hh[0];
    *(half8*)(Ahi + swz(r, (tid & 3) * 2 + 1)) = hh[1];
    *(half8*)(Alo + swz(r, (tid & 3) * 2 + 0)) = hl[0];
    *(half8*)(Alo + swz(r, (tid & 3) * 2 + 1)) = hl[1];
    // stage gw0T tile [32][64]
    int nb = tid >> 3, chb = tid & 7;
    half8 bh = *(const half8*)(g0hi + (size_t)nb * 576 + kt * 64 + chb * 8);
    half8 bl = *(const half8*)(g0lo + (size_t)nb * 576 + kt * 64 + chb * 8);
    *(half8*)(Bhi + swz(nb, chb)) = bh;
    *(half8*)(Blo + swz(nb, chb)) = bl;
    __syncthreads();
    // compute: wave handles rows wave*16..+16
#pragma unroll
    for (int ks = 0; ks < 2; ks++) {
      int arow = wave * 16 + (lane & 15);
      int ch = ks * 4 + (lane >> 4);
      half8 ah = *(const half8*)(Ahi + swz(arow, ch));
      half8 al = *(const half8*)(Alo + swz(arow, ch));
#pragma unroll
      for (int n = 0; n < 2; n++) {
        int brow = n * 16 + (lane & 15);
        half8 wh = *(const half8*)(Bhi + swz(brow, ch));
        half8 wl = *(const half8*)(Blo + swz(brow, ch));
        acc[n] = __builtin_amdgcn_mfma_f32_16x16x32_f16(ah, wh, acc[n], 0, 0, 0);
        acc[n] = __builtin_amdgcn_mfma_f32_16x16x32_f16(al, wh, acc[n], 0, 0, 0);
        acc[n] = __builtin_amdgcn_mfma_f32_16x16x32_f16(ah, wl, acc[n], 0, 0, 0);
      }
    }
  }
  // h1 = elu(.) -> LDS
#pragma unroll
  for (int n = 0; n < 2; n++)
#pragma unroll
    for (int i = 0; i < 4; i++) {
      int row = wave * 16 + (lane >> 4) * 4 + i;
      int col = n * 16 + (lane & 15);
      h_lds[row][col] = elu_f(acc[n][i]);
    }
  __syncthreads();
  // layer 1: h2 = elu(h1 @ gw1 + gb1)
  {
    int row = tid & 63, q = tid >> 6;
    float a2[8];
#pragma unroll
    for (int o = 0; o < 8; o++) a2[o] = gb1[q * 8 + o];
    for (int j = 0; j < 32; j++) {
      float v = h_lds[row][j];
#pragma unroll
      for (int o = 0; o < 8; o++) a2[o] = fmaf(v, gw1[j * 32 + q * 8 + o], a2[o]);
    }
    __syncthreads();
#pragma unroll
    for (int o = 0; o < 8; o++) h_lds[row][q * 8 + o] = elu_f(a2[o]);
  }
  __syncthreads();
  // layer 2 + softmax (wave 0 only; 64 rows)
  if (wave == 0) {
    float lg[6];
#pragma unroll
    for (int e = 0; e < 6; e++) lg[e] = gb2[e];
    for (int j = 0; j < 32; j++) {
      float v = h_lds[lane][j];
#pragma unroll
      for (int e = 0; e < 6; e++) lg[e] = fmaf(v, gw2[j * 6 + e], lg[e]);
    }
    float mx = lg[0];
#pragma unroll
    for (int e = 1; e < 6; e++) mx = fmaxf(mx, lg[e]);
    float s = 0.f, pc[6];
#pragma unroll
    for (int e = 0; e < 6; e++) { pc[e] = __expf(lg[e] - mx); s += pc[e]; }
    float inv = 1.0f / s;
#pragma unroll
    for (int e = 0; e < 6; e++) coefT[e * B_ + b0 + lane] = pc[e] * inv;
  }
}

// ---------------- main mixed-expert GEMM -----------------------------------------
// C[b, k] = sum_e coef[b,e] * ( X[b,:J] @ Wt[e][k][:J]^T + bias[e][k] )
// ks-outer / expert-inner(unrolled). Counted-vmcnt pipeline:
//   B tiles: 3-buffer LDS ring, depth-2 prefetch (issue B[t+2] each iter).
//   A tile: single buffer, staged at e==1, read at e==0 of next ks-group.
//   raw s_barrier (no compiler vmcnt(0) drain); per-e vmcnt(N) from issue pattern:
//   steady N = {4,4,8,8,4,4}; final ks-group N = {4,4,4,4,4,0}.
// MODE 0: out_act[b*ASTR + k] = f16(elu(C));  MODE 1: out_f32[b*512+k] = C + 0.05*eps
template <int J, int KOUT, int MODE>
__global__ __launch_bounds__(256, 2) void moe_gemm(
    const f16* __restrict__ act, const f16* __restrict__ wt,
    const float* __restrict__ coefT, const float* __restrict__ bias,
    f16* __restrict__ out_act, float* __restrict__ out_f32) {
  constexpr int NSUB = J / 64;
  constexpr int NTILE = KOUT / 128;
  __shared__ __align__(16) char sm[65536];  // As 16K | B ring 3x16K

  const int tid = threadIdx.x;
  const int lane = tid & 63;
  const int wv = tid >> 6;
  const int wr = wv >> 1, wc = wv & 1;
  // XCD-bijective block swizzle (grid % 8 == 0)
  const int nwg = gridDim.x;
  const int cpx = nwg >> 3;
  const int bid = (blockIdx.x & 7) * cpx + (blockIdx.x >> 3);
  const int b0 = (bid / NTILE) * 128;
  const int n0 = (bid % NTILE) * 128;

  // staging geometry: wave wv, issue i covers tile rows wv*32+i*8 .. +7, 128B each.
  // source column pre-swizzled so linear LDS image matches swz() reads.
  int srow[4], scol[4];
#pragma unroll
  for (int i = 0; i < 4; i++) {
    int r = wv * 32 + i * 8 + (lane >> 3);
    srow[i] = r;
    scol[i] = ((lane & 7) ^ (r & 7)) * 8;
  }

  char* const As = sm;

  auto stageA = [&](int ks) {
#pragma unroll
    for (int i = 0; i < 4; i++)
      gload16(act + (size_t)(b0 + srow[i]) * ASTR + ks * 64 + scol[i],
              As + (wv * 4 + i) * 1024);
  };
  auto stageB = [&](int e, int ks, int buf) {
    const f16* wb = wt + (size_t)e * KOUT * J;
    char* Bs = sm + 16384 + buf * 16384;
#pragma unroll
    for (int i = 0; i < 4; i++)
      gload16(wb + (size_t)(n0 + srow[i]) * J + ks * 64 + scol[i],
              Bs + (wv * 4 + i) * 1024);
  };

  // prologue: A[0], B[t=0], B[t=1]
  stageA(0);
  stageB(0, 0, 0);
  stageB(1, 0, 1);

  // per-A-fragment-row coef, all experts (compile-time indexed in unrolled loops)
  f16 cfh[E_][4];
#pragma unroll
  for (int e = 0; e < E_; e++)
#pragma unroll
    for (int m = 0; m < 4; m++)
      cfh[e][m] = (f16)coefT[e * B_ + b0 + wr * 64 + m * 16 + (lane & 15)];

  // acc init = bias mix: acc[m][n][i] = sum_e coef[e][row] * bias[e][col]
  f32x4 acc[4][4];
#pragma unroll
  for (int m = 0; m < 4; m++)
#pragma unroll
    for (int n = 0; n < 4; n++) {
      f32x4 z = {0.f, 0.f, 0.f, 0.f};
      acc[m][n] = z;
    }
#pragma unroll
  for (int e = 0; e < E_; e++) {
    float bv[4];
#pragma unroll
    for (int n = 0; n < 4; n++)
      bv[n] = bias[e * KOUT + n0 + wc * 64 + n * 16 + (lane & 15)];
#pragma unroll
    for (int m = 0; m < 4; m++)
#pragma unroll
      for (int i = 0; i < 4; i++) {
        float cv = coefT[e * B_ + b0 + wr * 64 + m * 16 + (lane >> 4) * 4 + i];
#pragma unroll
        for (int n = 0; n < 4; n++) acc[m][n][i] = fmaf(cv, bv[n], acc[m][n][i]);
      }
  }

  half8 afr[2][4];  // raw A fragments for current ks (persist across experts)

  // fragment read + scale + MFMA for one tile (e is unroll-constant after inlining)
  auto compute = [&](int buf, int e, bool loadA) {
    char* Bcur = sm + 16384 + buf * 16384;
    if (loadA) {
#pragma unroll
      for (int h = 0; h < 2; h++)
#pragma unroll
        for (int m = 0; m < 4; m++) {
          int row = wr * 64 + m * 16 + (lane & 15);
          afr[h][m] = *(const half8*)(As + swz(row, h * 4 + (lane >> 4)));
        }
    }
#pragma unroll
    for (int h = 0; h < 2; h++) {
      half8 bf[4], afs[4];
#pragma unroll
      for (int n = 0; n < 4; n++) {
        int rn = wc * 64 + n * 16 + (lane & 15);
        bf[n] = *(const half8*)(Bcur + swz(rn, h * 4 + (lane >> 4)));
      }
#pragma unroll
      for (int m = 0; m < 4; m++) afs[m] = afr[h][m] * splat8(cfh[e][m]);
      __builtin_amdgcn_s_setprio(1);
#pragma unroll
      for (int m = 0; m < 4; m++)
#pragma unroll
        for (int n = 0; n < 4; n++)
          acc[m][n] = __builtin_amdgcn_mfma_f32_16x16x32_f16(afs[m], bf[n], acc[m][n], 0, 0, 0);
      __builtin_amdgcn_s_setprio(0);
    }
  };

  // steady groups: ks = 0 .. NSUB-2
  for (int ks = 0; ks < NSUB - 1; ++ks) {
#pragma unroll
    for (int e = 0; e < 6; ++e) {
      // wait for tile t = ks*6+e (own 4 loads), leave younger loads in flight
      if (e == 2 || e == 3) { WAITVM(8); } else { WAITVM(4); }
      __builtin_amdgcn_s_barrier();
      // issue B[t+2] into ring slot (t+2)%3 == (e+2)%3
      stageB((e + 2) % 6, ks + (e + 2) / 6, (e + 2) % 3);
      if (e == 1) stageA(ks + 1);  // A readers (e==0) finished before this barrier
      compute(e % 3, e, e == 0);
    }
  }
  // final group: ks = NSUB-1 (no A issue; B[t+2] only for e<=3)
  {
    const int ks = NSUB - 1;
#pragma unroll
    for (int e = 0; e < 6; ++e) {
      if (e == 5) { WAITVM(0); } else { WAITVM(4); }
      __builtin_amdgcn_s_barrier();
      if (e <= 3) stageB(e + 2, ks, (e + 2) % 3);
      compute(e % 3, e, e == 0);
    }
  }

  // epilogue (bias+coef already folded in)
#pragma unroll
  for (int m = 0; m < 4; m++)
#pragma unroll
    for (int n = 0; n < 4; n++)
#pragma unroll
      for (int i = 0; i < 4; i++) {
        int row = b0 + wr * 64 + m * 16 + (lane >> 4) * 4 + i;
        int col = n0 + wc * 64 + n * 16 + (lane & 15);
        float x = acc[m][n][i];
        if (MODE == 0) {
          out_act[(size_t)row * ASTR + col] = (f16)elu_f(x);
        } else {
          u32 idx = (u32)row * AOUT + col;
          out_f32[idx] = fmaf(0.05f, jax_eps(idx), x);
        }
      }
}

// ---------------- launch ----------------------------------------------------------
extern "C" void kernel_launch(void* const* d_in, const int* in_sizes, int n_in,
                              void* d_out, int out_size, void* d_ws, size_t ws_size,
                              hipStream_t stream) {
  (void)in_sizes; (void)n_in; (void)out_size; (void)ws_size;
  const float* state  = (const float*)d_in[0];
  const float* latent = (const float*)d_in[1];
  const float* w0 = (const float*)d_in[2];
  const float* b0 = (const float*)d_in[3];
  const float* w1 = (const float*)d_in[4];
  const float* b1 = (const float*)d_in[5];
  const float* w2 = (const float*)d_in[6];
  const float* b2 = (const float*)d_in[7];
  const float* w3 = (const float*)d_in[8];
  const float* b3 = (const float*)d_in[9];
  const float* gw0 = (const float*)d_in[10];
  const float* gb0 = (const float*)d_in[11];
  const float* gw1 = (const float*)d_in[12];
  const float* gb1 = (const float*)d_in[13];
  const float* gw2 = (const float*)d_in[14];
  const float* gb2 = (const float*)d_in[15];

  char* ws = (char*)d_ws;
  size_t off = 0;
  float* coefT = (float*)(ws + off); off += (size_t)E_ * B_ * 4;
  f16* actA = (f16*)(ws + off); off += (size_t)B_ * ASTR * 2;
  f16* actB = (f16*)(ws + off); off += (size_t)B_ * ASTR * 2;
  f16* wt0 = (f16*)(ws + off); off += (size_t)E_ * 1024 * 576 * 2;
  f16* wt1 = (f16*)(ws + off); off += (size_t)E_ * 1024 * 1088 * 2;
  f16* wt2 = (f16*)(ws + off); off += (size_t)E_ * 1024 * 1088 * 2;
  f16* wt3 = (f16*)(ws + off); off += (size_t)E_ * 512 * 1088 * 2;
  f16* g0hi = (f16*)(ws + off); off += 32 * 576 * 2;
  f16* g0lo = (f16*)(ws + off); off += 32 * 576 * 2;

  prep_act<<<4608, 256, 0, stream>>>(state, latent, actA, actB);
  prep_gw0<<<72, 256, 0, stream>>>(gw0, g0hi, g0lo);
  transpose_w<<<6 * 9 * 16, 256, 0, stream>>>(w0, wt0, 576, 1024);
  transpose_w<<<6 * 17 * 16, 256, 0, stream>>>(w1, wt1, 1088, 1024);
  transpose_w<<<6 * 17 * 16, 256, 0, stream>>>(w2, wt2, 1088, 1024);
  transpose_w<<<6 * 17 * 8, 256, 0, stream>>>(w3, wt3, 1088, 512);
  gating_kernel<<<256, 256, 0, stream>>>(state, latent, g0hi, g0lo, gb0, gw1, gb1,
                                         gw2, gb2, coefT);
  moe_gemm<576, 1024, 0><<<1024, 256, 0, stream>>>(actA, wt0, coefT, b0, actB, nullptr);
  moe_gemm<1088, 1024, 0><<<1024, 256, 0, stream>>>(actB, wt1, coefT, b1, actA, nullptr);
  moe_gemm<1088, 1024, 0><<<1024, 256, 0, stream>>>(actA, wt2, coefT, b2, actB, nullptr);
  moe_gemm<1088, 512, 1><<<512, 256, 0, stream>>>(actB, wt3, coefT, b3, nullptr, (float*)d_out);
}